// Round 17
// baseline (330.475 us; speedup 1.0000x reference)
//
#include <hip/hip_runtime.h>
#include <hip/hip_bf16.h>
#include <math.h>

// B=4096 queries, D=256, K=65536 centroids (f32).
// Round 17 (this session): launch-count collapse 6 ops -> 3. Evidence: finish
// restructure null (327.1 vs 327.9) while phase arithmetic says finish <= 40us;
// r10->r11->r12 launch-count deltas imply ~12-15us/op overhead x 6 ops. Plan:
// (1) prep = splitc+splitx fused (17408 blocks) + per-block csq max via PLAIN
//     STORE ctl2[b] (r14's 191us was the single-dword atomic, not reduction);
// (2) scan: designated block (kc=0,y=0) reduces ctl2[16384]->ctl[32] (64KB,
//     hidden under other 511 blocks); + T5 probe: s_setprio(1) around the
//     MFMA/ds_read cluster (scan waves barrier-free + phase-staggered = the
//     regime where setprio paid; lockstep GEMM was null). scan # isolates it.
// (3) finish unchanged; hipMemsetAsync deleted (ctl plainly written each run).
// Predict: prep ~21, scan 153-162, total 290-310 if overhead theory holds;
// total>=320 -> overhead small, finish ablation next. Revert: absmax!=0 ->
// ctl2 path; scan>165 -> setprio.

#define DDIM 256
#define QTILE 128
#define STSZ 8192      // centroids per kc strip (16 ct x 512c; block covers 256c/ct)
#define QCAP 48        // candidate groups per query
#define F16_MINN 6.103515625e-5f

typedef __attribute__((ext_vector_type(8))) _Float16 half8;
typedef __attribute__((ext_vector_type(4))) _Float16 half4;
typedef __attribute__((ext_vector_type(4))) float f32x4;

__device__ __forceinline__ void gl_lds16(const void* g, void* l) {
  __builtin_amdgcn_global_load_lds((const __attribute__((address_space(1))) void*)g,
                                   (__attribute__((address_space(3))) void*)l, 16, 0, 0);
}

// exact order-preserving float -> uint key (finite floats; matches f32 <)
__device__ __forceinline__ unsigned fkey(float d) {
  unsigned ud = __float_as_uint(d);
  return ud ^ (((int)ud < 0) ? 0xFFFFFFFFu : 0x80000000u);
}

// ---------------- prep: splitc (+ per-block csq-max, plain store) + splitx ---------
// blocks 0..16383: centroid split (4 rows each) + c_sq + ctl2[b] = block max.
// blocks 16384..17407: x split.
__global__ __launch_bounds__(256) void prep_kernel(const float* __restrict__ cent,
                                                   const float* __restrict__ x,
                                                   _Float16* __restrict__ c0,
                                                   _Float16* __restrict__ x0,
                                                   float* __restrict__ c_sq,
                                                   float* __restrict__ ctl2) {
  const int b = (int)blockIdx.x;
  if (b < 16384) {
    __shared__ float red[4];
    int i = b * 256 + (int)threadIdx.x;   // 4-elem chunk id; wave = one row
    int lane = (int)threadIdx.x & 63, w = (int)threadIdx.x >> 6;
    float4 v = ((const float4*)cent)[i];
    float vv[4] = {v.x, v.y, v.z, v.w};
    half4 h0;
#pragma unroll
    for (int e = 0; e < 4; ++e)
      h0[e] = (fabsf(vv[e]) < F16_MINN) ? (_Float16)0.f : (_Float16)vv[e];
    *(half4*)(c0 + (size_t)i * 4) = h0;
    float s = fmaf(v.x, v.x, fmaf(v.y, v.y, fmaf(v.z, v.z, v.w * v.w)));
#pragma unroll
    for (int off = 32; off > 0; off >>= 1) s += __shfl_down(s, off, 64);
    if (lane == 0) { c_sq[i >> 6] = s; red[w] = s; }
    __syncthreads();
    if (threadIdx.x == 0)
      ctl2[b] = fmaxf(fmaxf(red[0], red[1]), fmaxf(red[2], red[3]));
  } else {
    int i = (b - 16384) * 256 + (int)threadIdx.x;   // < 262144 by construction
    float4 v = ((const float4*)x)[i];
    float vv[4] = {v.x, v.y, v.z, v.w};
    half4 h0;
#pragma unroll
    for (int e = 0; e < 4; ++e)
      h0[e] = (fabsf(vv[e]) < F16_MINN) ? (_Float16)0.f : (_Float16)vv[e];
    *(half4*)(x0 + (size_t)i * 4) = h0;
  }
}

// ---------------- scan: 16x16x32 f16 MFMA, 512-thr block, 2 blocks/CU, fused pm ----
// Wave w (0..7) owns c-slice chalf*256 + w*32 of each 512-c ct slice.
// A (centroids): lane l -> row l&15, k = (l>>4)*8 + e  (+kt*32)
// B (queries):   lane l -> col l&15, same k mapping
// C/D: col = lane&15 (query), row = (lane>>4)*4 + r  (centroid, within 16-tile).
// kc = blockIdx.x (fast): linear%8 = kc = XCD id -> each XCD owns ONE 4MB c0 strip.
// pmred[w][q]: per-wave running min over its 16 ct groups -> pm[kc*2+chalf][q].
// Designated block (kc==0,y==0) additionally reduces ctl2[16384] -> ctl[32].
__global__ __launch_bounds__(512, 4) void scan_kernel(
    const _Float16* __restrict__ x0, const _Float16* __restrict__ c0,
    const float* __restrict__ c_sq, float* __restrict__ dm,
    float* __restrict__ pm, const float* __restrict__ ctl2,
    unsigned* __restrict__ ctl) {
  __shared__ __align__(16) _Float16 As0[32768];   // 64 KiB: [s=kt*4+quad][q(128)][8]
  __shared__ float pmred[1024];                   // 4 KiB: [w(8)][q(128)]

  const int kc = blockIdx.x;                      // kc fast -> XCD-aligned strips
  const int qb = (int)blockIdx.y >> 1, chalf = (int)blockIdx.y & 1;
  const int tid = (int)threadIdx.x;
  const int lane = tid & 63, w = tid >> 6;        // w = 0..7
  const int col = lane & 15, quad = lane >> 4;
  const int qrow0 = qb * QTILE;

  if (kc == 0 && blockIdx.y == 0) {               // cmax reduce (hidden: 1/512 blocks)
    float m = 0.f;                                // c_sq >= 0
    const float4* c4 = (const float4*)ctl2;
#pragma unroll
    for (int i = 0; i < 8; ++i) {
      float4 v = c4[i * 512 + tid];
      m = fmaxf(fmaxf(m, fmaxf(v.x, v.y)), fmaxf(v.z, v.w));
    }
#pragma unroll
    for (int off = 32; off > 0; off >>= 1) m = fmaxf(m, __shfl_down(m, off, 64));
    if (lane == 0) pmred[w] = m;
    __syncthreads();
    if (tid == 0) {
      float mm = pmred[0];
#pragma unroll
      for (int i = 1; i < 8; ++i) mm = fmaxf(mm, pmred[i]);
      ctl[32] = __float_as_uint(mm);              // plain store, no init needed
    }
    __syncthreads();                              // before pmred re-init below
  }

  pmred[tid] = INFINITY;
  pmred[tid + 512] = INFINITY;

  // stage x tile: 4096 16B chunks; chunk u = s*128+q holds x0[qrow0+q][s*8 .. s*8+7]
#pragma unroll
  for (int i = 0; i < 8; ++i) {
    int u = i * 512 + tid;
    int q = u & 127, s = u >> 7;
    gl_lds16(x0 + (size_t)(qrow0 + q) * DDIM + s * 8, As0 + (size_t)u * 8);
  }
  __syncthreads();   // As0 + pmred ready

  for (int ct = 0; ct < STSZ / 512; ++ct) {
    const int cbase = kc * STSZ + ct * 512 + chalf * 256 + w * 32;  // 32-c group
    f32x4 acc[2][8];                                    // [cm][qn]
#pragma unroll
    for (int cm = 0; cm < 2; ++cm)
#pragma unroll
      for (int qn = 0; qn < 8; ++qn) acc[cm][qn] = (f32x4)0.0f;

#pragma unroll 2
    for (int kt = 0; kt < 8; ++kt) {
      const int k0 = kt * 32;
      half8 cf[2];
#pragma unroll
      for (int cm = 0; cm < 2; ++cm)
        cf[cm] = *(const half8*)(c0 + (size_t)(cbase + cm * 16 + col) * DDIM + k0 + quad * 8);
      __builtin_amdgcn_s_setprio(1);               // T5: favor MFMA/ds_read cluster
#pragma unroll
      for (int qn = 0; qn < 8; ++qn) {
        half8 qf = *(const half8*)(As0 + (size_t)(((kt * 4 + quad) * QTILE) + qn * 16 + col) * 8);
#pragma unroll
        for (int cm = 0; cm < 2; ++cm)
          acc[cm][qn] = __builtin_amdgcn_mfma_f32_16x16x32_f16(cf[cm], qf, acc[cm][qn], 0, 0, 0);
      }
      __builtin_amdgcn_s_setprio(0);
    }

    // epilogue: d = cs - 2*dot; min over 32 centroids (2 cm x 4 rg in-lane + quad xor)
    f32x4 csv[2];
#pragma unroll
    for (int cm = 0; cm < 2; ++cm)
      csv[cm] = *(const f32x4*)(c_sq + cbase + cm * 16 + quad * 4);
    const int grp = kc * (STSZ / 32) + ct * 16 + chalf * 8 + w;
    float* dmg = dm + (size_t)grp * 4096 + qrow0;
#pragma unroll
    for (int qn = 0; qn < 8; ++qn) {
      float mq = INFINITY;
#pragma unroll
      for (int cm = 0; cm < 2; ++cm)
#pragma unroll
        for (int rg = 0; rg < 4; ++rg)
          mq = fminf(mq, fmaf(-2.0f, acc[cm][qn][rg], csv[cm][rg]));
      mq = fminf(mq, __shfl_xor(mq, 16, 64));
      mq = fminf(mq, __shfl_xor(mq, 32, 64));
      if (quad == 0) {
        dmg[qn * 16 + col] = mq;                      // 16 lanes, 64 B dense
        const int pi = w * 128 + qn * 16 + col;       // banks: col -> 16 distinct
        pmred[pi] = fminf(pmred[pi], mq);
      }
    }
  }

  __syncthreads();
  if (tid < 128) {       // column-min over 8 wave rows -> pm[kc*2+chalf][q]
    float m = INFINITY;
#pragma unroll
    for (int i = 0; i < 8; ++i) m = fminf(m, pmred[i * 128 + tid]);
    pm[(size_t)(kc * 2 + chalf) * 4096 + qrow0 + tid] = m;
  }
}

// ---------------- finish: fused tq + emit + rescore + writeback ----------------
// Block = 8 queries (grid 512, 512 thr = 8 waves, 1 query per wave).
__global__ __launch_bounds__(512) void finish_kernel(
    const float* __restrict__ pm, const float* __restrict__ x,
    const unsigned* __restrict__ ctl, const float* __restrict__ dm,
    const float* __restrict__ cent, const float* __restrict__ c_sq,
    float* __restrict__ out) {
  __shared__ float Tl[8];
  __shared__ unsigned cnt8[8];
  __shared__ unsigned short candL[8][QCAP];
  __shared__ unsigned long long bestL[8];

  const int t = (int)threadIdx.x;
  const int w = t >> 6, lane = t & 63;
  const int q0 = (int)blockIdx.x * 8;

  // ph1: wave w computes xsq for query q0+w (one float4/lane), then T
  {
    float4 v = ((const float4*)(x + (size_t)(q0 + w) * DDIM))[lane];
    float s = fmaf(v.x, v.x, fmaf(v.y, v.y, fmaf(v.z, v.z, v.w * v.w)));
#pragma unroll
    for (int off = 32; off > 0; off >>= 1) s += __shfl_down(s, off, 64);
    if (lane == 0) {
      float M = INFINITY;
#pragma unroll
      for (int i = 0; i < 16; ++i) M = fminf(M, pm[i * 4096 + q0 + w]);
      float cmaxsq = __uint_as_float(ctl[32]);
      // rigorous 1-term f16 bound ~2^-9 ||x|| ||c||max; margin = 4x bound + 1.0 slack
      Tl[w] = M + 0.0078125f * sqrtf(s * cmaxsq) + 1.0f;
      cnt8[w] = 0u;
    }
  }
  __syncthreads();

  // ph2: emit (qi = t&7, g0 = t>>3; 32B dm segments; order-invariant min-over-set)
  {
    const int qi = t & 7, g0 = t >> 3;
    const float Tq = Tl[qi];
#pragma unroll 4
    for (int i = 0; i < 32; ++i) {
      int g = g0 + i * 64;
      float v = dm[(size_t)g * 4096 + q0 + qi];
      if (v <= Tq) {
        unsigned slot = atomicAdd(&cnt8[qi], 1u);
        if (slot < QCAP) candL[qi][slot] = (unsigned short)g;
      }
    }
  }
  __syncthreads();

  // ph3: wave w rescores query q0+w (1:1, no serialization)
  {
    const unsigned n = cnt8[w];
    unsigned long long bq = 0xFFFFFFFFFFFFFFFFull;
    if (n >= 1 && n <= QCAP) {
      int dh = (lane & 1) * 128;
      const float4* xr = (const float4*)(x + (size_t)(q0 + w) * DDIM + dh);
      for (unsigned sl = 0; sl < n; ++sl) {
        int g = (int)candL[w][sl];
        int c = g * 32 + (lane >> 1);
        const float4* cr = (const float4*)(cent + (size_t)c * DDIM + dh);
        float s = 0.f;
#pragma unroll
        for (int i = 0; i < 32; ++i) {
          float4 a = xr[i], bb = cr[i];
          s = fmaf(a.x, bb.x, fmaf(a.y, bb.y, fmaf(a.z, bb.z, fmaf(a.w, bb.w, s))));
        }
        s += __shfl_xor(s, 1, 64);
        float d = (lane & 1) ? INFINITY : fmaf(-2.0f, s, c_sq[c]);
        unsigned long long pkv = ((unsigned long long)fkey(d) << 32) | (unsigned)c;
        if (pkv < bq) bq = pkv;
      }
    } else {
      // safety net: exact argmin over all 65536 (overflow; should never trigger)
      const float4* xr = (const float4*)(x + (size_t)(q0 + w) * DDIM);
      for (int c = lane; c < 65536; c += 64) {
        const float4* cr = (const float4*)(cent + (size_t)c * DDIM);
        float s = 0.f;
#pragma unroll 16
        for (int i = 0; i < 64; ++i) {
          float4 a = xr[i], bb = cr[i];
          s = fmaf(a.x, bb.x, fmaf(a.y, bb.y, fmaf(a.z, bb.z, fmaf(a.w, bb.w, s))));
        }
        float d = fmaf(-2.0f, s, c_sq[c]);
        unsigned long long pkv = ((unsigned long long)fkey(d) << 32) | (unsigned)c;
        if (pkv < bq) bq = pkv;
      }
    }
#pragma unroll
    for (int off = 1; off < 64; off <<= 1) {
      unsigned long long o = __shfl_xor(bq, off, 64);
      if (o < bq) bq = o;
    }
    if (lane == 0) bestL[w] = bq;
  }
  __syncthreads();

  // writeback: wave w writes query q0+w's row (one float4 per lane) + code scalar
  {
    int idx = (int)(unsigned)(bestL[w] & 0xFFFFFFFFu);
    float4 v = ((const float4*)(cent + (size_t)idx * DDIM))[lane];
    ((float4*)(out + (size_t)(q0 + w) * DDIM))[lane] = v;
    if (lane == 0) out[(size_t)4096 * DDIM + q0 + w] = (float)idx;
  }
}

extern "C" void kernel_launch(void* const* d_in, const int* in_sizes, int n_in,
                              void* d_out, int out_size, void* d_ws, size_t ws_size,
                              hipStream_t stream) {
  const float* x    = (const float*)d_in[1];   // [4096,256]
  const float* cent = (const float*)d_in[2];   // [65536,256]
  float* out = (float*)d_out;
  char* ws = (char*)d_ws;

  const size_t OFF_C0   = 0;           // 33,554,432  f16 hi(centroids)
  const size_t OFF_X0   = 33554432;    //  2,097,152  f16 hi(x)
  const size_t OFF_CSQ  = 35651584;    //    262,144
  const size_t OFF_CTL  = 35913728;    //        256
  const size_t OFF_DM   = 35913984;    // 33,554,432  f32[2048][4096]
  const size_t OFF_PM   = 69468416;    //    262,144  f32[16][4096]
  const size_t OFF_CTL2 = 69730560;    //     65,536  f32[16384] per-block csq max
  const size_t NEED     = 72089600;    // proven available since round 2
  if (ws_size < NEED) return;

  _Float16* c0 = (_Float16*)(ws + OFF_C0);
  _Float16* x0 = (_Float16*)(ws + OFF_X0);
  float* c_sq = (float*)(ws + OFF_CSQ);
  unsigned* ctl = (unsigned*)(ws + OFF_CTL);
  float* dm = (float*)(ws + OFF_DM);
  float* pm = (float*)(ws + OFF_PM);
  float* ctl2 = (float*)(ws + OFF_CTL2);

  prep_kernel<<<17408, 256, 0, stream>>>(cent, x, c0, x0, c_sq, ctl2);
  scan_kernel<<<dim3(8, 64), 512, 0, stream>>>(x0, c0, c_sq, dm, pm, ctl2, ctl);
  finish_kernel<<<512, 512, 0, stream>>>(pm, x, ctl, dm, cent, c_sq, out);
}